// Round 15
// 136.263 us; speedup vs baseline: 6.0737x; 1.1354x over previous
//
#include <hip/hip_runtime.h>
#include <cstdint>

// ---------------------------------------------------------------------------
// SS-MSA fused implementation, round 15 (= round 14 + conv staging
// vectorization; pure copy-width change, bit-identical values).
// grid_shift(sim) factorizes: shifted[i,j] = SCALE*(q_{i-1}.k_{j-1} + q~_i.k~_j) + P[i,j]
// => both branches are plain attention with 56-dim augmented Q/K + bias P.
//
// Round-15 changes vs round 14 (passing, 154.7us):
//  - k_conv1 staging: 693 uint2 tasks (was 11088 scalar u16 ld+st =
//    ~11M scalar VMEM issues across the dispatch); zero-pad as uint2.
//  - k_conv2 staging: 1584 uint2 tasks (was 6336 scalar).
//  All addresses 8B-aligned: ssum row stride 112B, br*56B, 8*c4; c1o row
//  stride 32B; LDS tile strides 72B/40B.
// ---------------------------------------------------------------------------

#define SCALE_ 0.18898223650461364f  // 28^-0.5

using f4 = __attribute__((ext_vector_type(4))) float;
using bf4 = __attribute__((ext_vector_type(4))) short;

__device__ __forceinline__ f4 mfma16(bf4 a, bf4 b, f4 c) {
#if __has_builtin(__builtin_amdgcn_mfma_f32_16x16x16bf16_1k)
    return __builtin_amdgcn_mfma_f32_16x16x16bf16_1k(a, b, c, 0, 0, 0);
#else
    f4 d;
    asm("v_mfma_f32_16x16x16_bf16 %0, %1, %2, %3" : "=v"(d) : "v"(a), "v"(b), "v"(c));
    return d;
#endif
}

__device__ __forceinline__ unsigned pk_bf16(float lo, float hi) {
    unsigned r;
    asm("v_cvt_pk_bf16_f32 %0, %1, %2" : "=v"(r) : "v"(lo), "v"(hi));
    return r;
}
__device__ __forceinline__ unsigned short f2bf(float f) {
    return (unsigned short)pk_bf16(f, f);
}
__device__ __forceinline__ float bf2f(unsigned short h) {
    return __uint_as_float(((unsigned)h) << 16);
}
__device__ __forceinline__ bf4 pack4(float a, float b, float c, float d) {
    union { unsigned u[2]; bf4 v; } cv;
    cv.u[0] = pk_bf16(a, b);
    cv.u[1] = pk_bf16(c, d);
    return cv.v;
}

__device__ __forceinline__ void coords_(int idx, int S, float s,
                                        int& i0, int& i1, float& w0, float& w1) {
    float g = -1.0f + 2.0f * (float)idx / (float)(S - 1);
    float c = (g + s * 2.0f / (float)S + 1.0f) * 0.5f * (float)(S - 1);
    float span = (float)(S - 1);
    c = fabsf(c);
    c = fmodf(c, 2.0f * span);
    if (c > span) c = 2.0f * span - c;
    int f = (int)floorf(c);
    f = max(0, min(f, S - 1));
    i0 = f;
    i1 = min(f + 1, S - 1);
    w1 = c - (float)f;
    w0 = 1.0f - w1;
}

// ------------------ K0: weight prep (fragment-ordered bf16) ----------------
__global__ __launch_bounds__(256) void k_prep(const float* __restrict__ Wq,
                                              const float* __restrict__ Wkv,
                                              const float* __restrict__ Wout,
                                              const float* __restrict__ c1w,
                                              const float* __restrict__ c2w,
                                              unsigned short* __restrict__ WF,
                                              unsigned short* __restrict__ WFo,
                                              unsigned short* __restrict__ BF1,
                                              unsigned short* __restrict__ BF2) {
    int tid = blockIdx.x * 256 + threadIdx.x;
    if (tid < 11264) {
        int e = tid & 3;
        int l = (tid >> 2) & 63;
        int kt = (tid >> 8) & 3;
        int nt = tid >> 10;
        int g = l >> 4, li = l & 15;
        int k = 16 * kt + 4 * g + e;
        int col = 16 * nt + li;
        float v = 0.f;
        if (k < 56 && col < 168)
            v = (col < 56) ? Wq[k * 56 + col] : Wkv[k * 112 + (col - 56)];
        WF[tid] = f2bf(v);
    } else if (tid < 15360) {
        int t2 = tid - 11264;
        int e = t2 & 3;
        int l = (t2 >> 2) & 63;
        int kt = (t2 >> 8) & 3;
        int nt = t2 >> 10;
        int g = l >> 4, li = l & 15;
        int k = 16 * kt + 4 * g + e;
        int col = 16 * nt + li;
        float v = (k < 56 && col < 56) ? Wout[k * 56 + col] : 0.f;
        WFo[t2] = f2bf(v);
    } else if (tid < 19968) {
        int t2 = tid - 15360;  // 4608 entries
        int e = t2 & 3;
        int l = (t2 >> 2) & 63;
        int rest = t2 >> 8;    // t*2+kg
        int kg = rest & 1;
        int t = rest >> 1;
        int g = l >> 4, li = l & 15;
        int c = 16 * kg + 4 * g + e;
        float v = (c < 28) ? c1w[li * 252 + c * 9 + t] : 0.f;
        unsigned short h = f2bf(v);
        BF1[t2] = h;
        BF1[4608 + t2] = f2bf(v - bf2f(h));
    } else if (tid < 22272) {
        int t2 = tid - 19968;  // 2304 entries
        int e = t2 & 3;
        int l = (t2 >> 2) & 63;
        int t = t2 >> 8;
        int g = l >> 4, li = l & 15;
        int c = 4 * g + e;
        float v = c2w[li * 144 + c * 9 + t];
        unsigned short h = f2bf(v);
        BF2[t2] = h;
        BF2[2304 + t2] = f2bf(v - bf2f(h));
    }
}

// ------------------- K1: QKV GEMM (bf16 MFMA, prepped B) -------------------
__global__ __launch_bounds__(256) void k_qkv(const float* __restrict__ x,
                                             const unsigned short* __restrict__ WF,
                                             unsigned short* __restrict__ q1,
                                             unsigned short* __restrict__ k1,
                                             unsigned short* __restrict__ v1,
                                             unsigned short* __restrict__ q2,
                                             unsigned short* __restrict__ k2,
                                             unsigned short* __restrict__ v2,
                                             unsigned short* __restrict__ ssum) {
    extern __shared__ __align__(16) char smem[];
    unsigned short* Ah = (unsigned short*)smem;            // [64][68]
    unsigned short* st = (unsigned short*)(smem + 8704);   // [64][172]
    int tid = threadIdx.x;
    int w = tid >> 6;
    int l = tid & 63;
    int g = l >> 4;
    int li = l & 15;
    int pix0 = blockIdx.x * 64;
    for (int e = tid; e < 896; e += 256) {
        int row = e / 14;
        int c4 = (e - row * 14) * 4;
        float4 v = *(const float4*)(x + (size_t)pix0 * 56 + 4 * e);
        uint2 p;
        p.x = pk_bf16(v.x, v.y);
        p.y = pk_bf16(v.z, v.w);
        *(uint2*)((unsigned*)Ah + row * 34 + (c4 >> 1)) = p;
    }
    for (int e = tid; e < 384; e += 256) {
        int row = e / 6;
        ((unsigned*)Ah)[row * 34 + 28 + (e - row * 6)] = 0;
    }
    int nt0 = 3 * w;
    int nnt = (w < 3) ? 3 : 2;
    bf4 B[3][4];
#pragma unroll
    for (int t = 0; t < 3; ++t) {
        if (t >= nnt) break;
#pragma unroll
        for (int kt = 0; kt < 4; ++kt)
            B[t][kt] = *(const bf4*)(WF + (((nt0 + t) * 4 + kt) * 64 + l) * 4);
    }
    __syncthreads();
    f4 acc[4][3];
#pragma unroll
    for (int mi = 0; mi < 4; ++mi)
#pragma unroll
        for (int t = 0; t < 3; ++t) acc[mi][t] = (f4){0.f, 0.f, 0.f, 0.f};
#pragma unroll
    for (int mi = 0; mi < 4; ++mi) {
        bf4 a[4];
#pragma unroll
        for (int kt = 0; kt < 4; ++kt)
            a[kt] = *(const bf4*)(Ah + (16 * mi + li) * 68 + 16 * kt + 4 * g);
#pragma unroll
        for (int t = 0; t < 3; ++t) {
            if (t >= nnt) break;
#pragma unroll
            for (int kt = 0; kt < 4; ++kt)
                acc[mi][t] = mfma16(a[kt], B[t][kt], acc[mi][t]);
        }
    }
#pragma unroll
    for (int mi = 0; mi < 4; ++mi)
#pragma unroll
        for (int t = 0; t < 3; ++t) {
            if (t >= nnt) break;
            int col = 16 * (nt0 + t) + li;
            if (col < 168) {
#pragma unroll
                for (int r = 0; r < 4; ++r)
                    st[(16 * mi + 4 * g + r) * 172 + col] = f2bf(acc[mi][t][r]);
            }
        }
    __syncthreads();
    // ---- ssum: one (row, 14-col slice) per thread; st cols: q|k|v at 0/56/112
    {
        int row = tid >> 2;
        int qq = tid & 3;
        int pixel = pix0 + row;
        int b = pixel >> 14;
        int rem = pixel & 16383;
        int hh = rem >> 7;
        int ww = rem & 127;
        int n = ((hh >> 3) << 4) + (ww >> 3);
        int m = ((hh & 7) << 3) + (ww & 7);
        size_t ob = ((size_t)(b * 256 + n) * 64 + m) * 56 + 14 * qq;
        const unsigned short* sr = st + row * 172 + 14 * qq;
#pragma unroll
        for (int h = 0; h < 7; ++h) {
            unsigned qw = *(const unsigned*)(sr + 2 * h);
            unsigned kw = *(const unsigned*)(sr + 56 + 2 * h);
            unsigned vw = *(const unsigned*)(sr + 112 + 2 * h);
            float s0 = __uint_as_float(qw << 16) + __uint_as_float(kw << 16) +
                       __uint_as_float(vw << 16);
            float s1 = __uint_as_float(qw & 0xffff0000u) + __uint_as_float(kw & 0xffff0000u) +
                       __uint_as_float(vw & 0xffff0000u);
            *(unsigned*)(ssum + ob + 2 * h) = pk_bf16(s0, s1);
        }
    }
    // ---- array half-rows: 384 tasks of 7 uint2 copies ----
    for (int e = tid; e < 384; e += 256) {
        int row = e / 6;
        int half = e - row * 6;
        int pixel = pix0 + row;
        int b = pixel >> 14;
        int rem = pixel & 16383;
        int hh = rem >> 7;
        int ww = rem & 127;
        int n = ((hh >> 3) << 4) + (ww >> 3);
        int m = ((hh & 7) << 3) + (ww & 7);
        size_t p1 = ((size_t)(b * 256 + n) * 64 + m) * 28;
        size_t p2 = ((size_t)(b * 64 + m) * 256 + n) * 28;
        unsigned short* base =
            (half < 2) ? (half == 0 ? q1 + p1 : q2 + p2)
                       : (half < 4) ? (half == 2 ? k1 + p1 : k2 + p2)
                                    : (half == 4 ? v1 + p1 : v2 + p2);
        const unsigned short* src = st + row * 172 + half * 28;
#pragma unroll
        for (int h = 0; h < 7; ++h)
            *(uint2*)(base + 4 * h) = *(const uint2*)(src + 4 * h);
    }
}

// ---------------- K2: conv1, implicit-GEMM MFMA (bf16, hi/lo B) ------------
__global__ __launch_bounds__(256) void k_conv1(const unsigned short* __restrict__ ssum,
                                               const unsigned short* __restrict__ BF1,
                                               const float* __restrict__ c1b,
                                               unsigned short* __restrict__ c1o) {
    __shared__ __align__(16) unsigned short tile[6 * 66 * 36];
    int tid = threadIdx.x;
    int w = tid >> 6;
    int l = tid & 63;
    int g = l >> 4;
    int li = l & 15;
    int wg = blockIdx.x;
    int br = wg >> 9;
    int b = (wg >> 6) & 7;
    int nt = wg & 63;
    int n0 = nt * 4;
    // staging: 693 uint2 tasks (4 channels each); all addresses 8B-aligned
    for (int e = tid; e < 2772; e += 256) {
        int c4 = e % 7;
        int rest = e / 7;
        int mm = rest % 66;
        int nr = rest / 66;
        int n = n0 - 1 + nr;
        int m = mm - 1;
        uint2 v = make_uint2(0u, 0u);
        if (n >= 0 && n < 256 && m >= 0 && m < 64)
            v = *(const uint2*)(ssum + (((size_t)b * 256 + n) * 64 + m) * 56 + br * 28 + 4 * c4);
        *(uint2*)(tile + (nr * 66 + mm) * 36 + 4 * c4) = v;
    }
    for (int e = tid; e < 396; e += 256)
        *(uint2*)(tile + e * 36 + 28) = make_uint2(0u, 0u);
    bf4 Bh[9][2], Bl[9][2];
#pragma unroll
    for (int t = 0; t < 9; ++t)
#pragma unroll
        for (int kg = 0; kg < 2; ++kg) {
            Bh[t][kg] = *(const bf4*)(BF1 + ((t * 2 + kg) * 64 + l) * 4);
            Bl[t][kg] = *(const bf4*)(BF1 + 4608 + ((t * 2 + kg) * 64 + l) * 4);
        }
    __syncthreads();
    f4 acc[4];
#pragma unroll
    for (int mt = 0; mt < 4; ++mt) acc[mt] = (f4){0.f, 0.f, 0.f, 0.f};
#pragma unroll
    for (int mt = 0; mt < 4; ++mt) {
#pragma unroll
        for (int t = 0; t < 9; ++t) {
            int ky = t / 3, kx = t - 3 * (t / 3);
#pragma unroll
            for (int kg = 0; kg < 2; ++kg) {
                bf4 a = *(const bf4*)(tile + ((w + ky) * 66 + 16 * mt + li + kx) * 36 +
                                      16 * kg + 4 * g);
                acc[mt] = mfma16(a, Bh[t][kg], acc[mt]);
                acc[mt] = mfma16(a, Bl[t][kg], acc[mt]);
            }
        }
    }
    float bias = c1b[li];
    size_t combo = (size_t)(br * 8 + b);
#pragma unroll
    for (int mt = 0; mt < 4; ++mt)
#pragma unroll
        for (int r = 0; r < 4; ++r) {
            int m = 16 * mt + 4 * g + r;
            float v = fmaxf(acc[mt][r] + bias, 0.f);
            c1o[(combo * 16384 + (size_t)(n0 + w) * 64 + m) * 16 + li] = f2bf(v);
        }
}

// ------------- K3: conv2 + pooled partials, implicit-GEMM MFMA -------------
__global__ __launch_bounds__(256) void k_conv2(const unsigned short* __restrict__ c1o,
                                               const unsigned short* __restrict__ BF2,
                                               const float* __restrict__ c2b,
                                               float* __restrict__ part) {
    __shared__ __align__(16) unsigned short tile[6 * 66 * 20];
    __shared__ float pbuf[4][16];
    int tid = threadIdx.x;
    int w = tid >> 6;
    int l = tid & 63;
    int g = l >> 4;
    int li = l & 15;
    int wg = blockIdx.x;
    int br = wg >> 9;
    int b = (wg >> 6) & 7;
    int nt = wg & 63;
    int n0 = nt * 4;
    size_t combo = (size_t)(br * 8 + b);
    // staging: 1584 uint2 tasks (4 channels each); 8B-aligned
    for (int e = tid; e < 1584; e += 256) {
        int c4 = e & 3;
        int rest = e >> 2;
        int mm = rest % 66;
        int nr = rest / 66;
        int n = n0 - 1 + nr;
        int m = mm - 1;
        uint2 v = make_uint2(0u, 0u);
        if (n >= 0 && n < 256 && m >= 0 && m < 64)
            v = *(const uint2*)(c1o + (combo * 16384 + (size_t)n * 64 + m) * 16 + 4 * c4);
        *(uint2*)(tile + (nr * 66 + mm) * 20 + 4 * c4) = v;
    }
    bf4 Bh[9], Bl[9];
#pragma unroll
    for (int t = 0; t < 9; ++t) {
        Bh[t] = *(const bf4*)(BF2 + (t * 64 + l) * 4);
        Bl[t] = *(const bf4*)(BF2 + 2304 + (t * 64 + l) * 4);
    }
    __syncthreads();
    f4 acc[4];
#pragma unroll
    for (int mt = 0; mt < 4; ++mt) acc[mt] = (f4){0.f, 0.f, 0.f, 0.f};
#pragma unroll
    for (int mt = 0; mt < 4; ++mt) {
#pragma unroll
        for (int t = 0; t < 9; ++t) {
            int ky = t / 3, kx = t - 3 * (t / 3);
            bf4 a = *(const bf4*)(tile + ((w + ky) * 66 + 16 * mt + li + kx) * 20 + 4 * g);
            acc[mt] = mfma16(a, Bh[t], acc[mt]);
            acc[mt] = mfma16(a, Bl[t], acc[mt]);
        }
    }
    float bias = c2b[li];
    float s = 0.f;
#pragma unroll
    for (int mt = 0; mt < 4; ++mt)
#pragma unroll
        for (int r = 0; r < 4; ++r) s += fmaxf(acc[mt][r] + bias, 0.f);
    s += __shfl_xor(s, 16);
    s += __shfl_xor(s, 32);
    if (l < 16) pbuf[w][li] = s;
    __syncthreads();
    if (tid < 16) {
        float tot = pbuf[0][tid] + pbuf[1][tid] + pbuf[2][tid] + pbuf[3][tid];
        part[(combo * 64 + nt) * 16 + tid] = tot;
    }
}

// ------------------------- K4: reduce + FC -> shifts -----------------------
__global__ void k_fc(const float* __restrict__ part, const float* __restrict__ f1w,
                     const float* __restrict__ f1b, const float* __restrict__ f2w,
                     const float* __restrict__ f2b, float* __restrict__ shif) {
    __shared__ float sb[16][16];
    int t = threadIdx.x;
    int combo = t >> 4;
    int o = t & 15;
    float s = 0.f;
    for (int nt = 0; nt < 64; ++nt) s += part[((size_t)combo * 64 + nt) * 16 + o];
    sb[combo][o] = s * (1.0f / 16384.0f);
    __syncthreads();
    if (t < 16) {
        float p0 = f1b[0], p1 = f1b[1], rg = f2b[0];
        for (int oo = 0; oo < 16; ++oo) {
            float sv = sb[t][oo];
            p0 += sv * f1w[oo * 2 + 0];
            p1 += sv * f1w[oo * 2 + 1];
            rg += sv * f2w[oo];
        }
        shif[t * 2 + 0] = rg * tanhf(p0);
        shif[t * 2 + 1] = rg * tanhf(p1);
    }
}

// ----------------- K5: shifted pos precompute (pos2 | pos1) ----------------
__global__ __launch_bounds__(256) void k_pos(const float* __restrict__ pos1,
                                             const float* __restrict__ pos2,
                                             const float* __restrict__ shif,
                                             float* __restrict__ P1T,
                                             float* __restrict__ P1M,
                                             float* __restrict__ P2R,
                                             float* __restrict__ P2M) {
    __shared__ float plds[64 * 64];
    if (blockIdx.x < 2048) {
        int wg = blockIdx.x;
        int b = wg >> 8;
        int i = wg & 255;
        float sx = shif[16 + b * 2 + 0];
        float sy = shif[16 + b * 2 + 1];
        int j = threadIdx.x;
        int y0, y1, x0, x1;
        float wy0, wy1, wx0, wx1;
        coords_(i, 256, sy, y0, y1, wy0, wy1);
        coords_(j, 256, sx, x0, x1, wx0, wx1);
        float v = pos2[((i - 1) & 255) * 256 + ((j - 1) & 255)] +
                  wy0 * (wx0 * pos2[y0 * 256 + x0] + wx1 * pos2[y0 * 256 + x1]) +
                  wy1 * (wx0 * pos2[y1 * 256 + x0] + wx1 * pos2[y1 * 256 + x1]);
        P2R[(size_t)b * 65536 + (size_t)i * 256 + j] = v;
        float mx = v;
#pragma unroll
        for (int msk = 1; msk < 64; msk <<= 1) mx = fmaxf(mx, __shfl_xor(mx, msk));
        if ((threadIdx.x & 63) == 0) plds[threadIdx.x >> 6] = mx;
        __syncthreads();
        if (threadIdx.x == 0)
            P2M[b * 256 + i] = fmaxf(fmaxf(plds[0], plds[1]), fmaxf(plds[2], plds[3]));
    } else {
        int b = blockIdx.x - 2048;
        float sx = shif[b * 2 + 0];
        float sy = shif[b * 2 + 1];
        for (int e = threadIdx.x; e < 4096; e += 256) {
            int j = e >> 6;
            int i = e & 63;
            int y0, y1, x0, x1;
            float wy0, wy1, wx0, wx1;
            coords_(i, 64, sy, y0, y1, wy0, wy1);
            coords_(j, 64, sx, x0, x1, wx0, wx1);
            float v = pos1[((i - 1) & 63) * 64 + ((j - 1) & 63)] +
                      wy0 * (wx0 * pos1[y0 * 64 + x0] + wx1 * pos1[y0 * 64 + x1]) +
                      wy1 * (wx0 * pos1[y1 * 64 + x0] + wx1 * pos1[y1 * 64 + x1]);
            P1T[(size_t)b * 4096 + j * 64 + i] = v;
            plds[j * 64 + i] = v;
        }
        __syncthreads();
        if (threadIdx.x < 64) {
            float mx = plds[threadIdx.x];
            for (int j = 1; j < 64; ++j) mx = fmaxf(mx, plds[j * 64 + threadIdx.x]);
            P1M[b * 64 + threadIdx.x] = mx;
        }
    }
}

// ---------------- K5c: transpose P2R -> P2T[b][j][i] (64x64 tiles) ---------
__global__ __launch_bounds__(256) void k_posT(const float* __restrict__ P2R,
                                              float* __restrict__ P2T) {
    __shared__ float t[64][65];
    int blk = blockIdx.x;     // 128 = 8 b x 16 tiles
    int b = blk >> 4;
    int t4 = blk & 15;
    int i0 = (t4 >> 2) * 64;
    int j0 = (t4 & 3) * 64;
    int tr = threadIdx.x >> 6;
    int tc = threadIdx.x & 63;
    for (int rr = 0; rr < 64; rr += 4)
        t[rr + tr][tc] = P2R[(size_t)b * 65536 + (size_t)(i0 + rr + tr) * 256 + j0 + tc];
    __syncthreads();
    for (int rr = 0; rr < 64; rr += 4)
        P2T[(size_t)b * 65536 + (size_t)(j0 + rr + tr) * 256 + i0 + tc] = t[tc][rr + tr];
}

// --------------- K6: branch-1 window attention (64x64), MFMA ---------------
__global__ __launch_bounds__(256) void k_attn1(const unsigned short* __restrict__ q1,
                                               const unsigned short* __restrict__ k1,
                                               const unsigned short* __restrict__ v1,
                                               const float* __restrict__ P1T,
                                               const float* __restrict__ P1M,
                                               const float* __restrict__ shif,
                                               unsigned short* __restrict__ aout) {
    __shared__ __align__(16) unsigned short qraw[64 * 28];
    __shared__ __align__(16) unsigned short kraw[64 * 28];
    __shared__ __align__(16) unsigned short augK[64 * 68];
    __shared__ __align__(16) unsigned short vT[32 * 68];
    __shared__ __align__(16) unsigned short Pw[4][16 * 68];
    int tid = threadIdx.x;
    int w = tid >> 6;
    int l = tid & 63;
    int g = l >> 4;
    int li = l & 15;
    int wg = blockIdx.x;
    int b = wg >> 8;
    int n = wg & 255;
    size_t gb = (size_t)(b * 256 + n) * 1792;
    float sx = shif[b * 2 + 0];
    float sy = shif[b * 2 + 1];
    for (int e = tid; e < 448; e += 256) {
        *(uint2*)(qraw + 4 * e) = *(const uint2*)(q1 + gb + 4 * e);
        *(uint2*)(kraw + 4 * e) = *(const uint2*)(k1 + gb + 4 * e);
        uint2 t = *(const uint2*)(v1 + gb + 4 * e);
        int idx = 4 * e;
        int j0 = idx / 28, c0 = idx - 28 * j0;
        int j1 = (idx + 1) / 28, c1 = (idx + 1) - 28 * j1;
        int j2 = (idx + 2) / 28, c2 = (idx + 2) - 28 * j2;
        int j3 = (idx + 3) / 28, c3 = (idx + 3) - 28 * j3;
        vT[c0 * 68 + j0] = (unsigned short)t.x;
        vT[c1 * 68 + j1] = (unsigned short)(t.x >> 16);
        vT[c2 * 68 + j2] = (unsigned short)t.y;
        vT[c3 * 68 + j3] = (unsigned short)(t.y >> 16);
    }
    for (int e = tid; e < 272; e += 256) vT[28 * 68 + e] = 0;
    __syncthreads();
    if (tid < 64) {
        int j = tid;
        int x0, x1;
        float wx0, wx1;
        coords_(j, 64, sx, x0, x1, wx0, wx1);
        int rm = (j - 1) & 63;
        uint2* rowv = (uint2*)(augK + j * 68);
        const uint2* srcv = (const uint2*)(kraw + rm * 28);
#pragma unroll
        for (int h = 0; h < 7; ++h) rowv[h] = srcv[h];
        unsigned* row = (unsigned*)(augK + j * 68);
#pragma unroll
        for (int h = 0; h < 14; ++h) {
            float a0 = wx0 * bf2f(kraw[x0 * 28 + 2 * h]) + wx1 * bf2f(kraw[x1 * 28 + 2 * h]);
            float a1 = wx0 * bf2f(kraw[x0 * 28 + 2 * h + 1]) + wx1 * bf2f(kraw[x1 * 28 + 2 * h + 1]);
            row[14 + h] = pk_bf16(a0, a1);
        }
#pragma unroll
        for (int h = 28; h < 34; ++h) row[h] = 0;
    }
    bf4 qf[4];
    {
        int i = 16 * w + li;
        int y0, y1;
        float wy0, wy1;
        coords_(i, 64, sy, y0, y1, wy0, wy1);
        int rm = (i - 1) & 63;
#pragma unroll
        for (int kt = 0; kt < 4; ++kt) {
            float qv[4];
#pragma unroll
            for (int e = 0; e < 4; ++e) {
                int d = 16 * kt + 4 * g + e;
                float v;
                if (d < 28) v = SCALE_ * bf2f(qraw[rm * 28 + d]);
                else if (d < 56)
                    v = SCALE_ * (wy0 * bf2f(qraw[y0 * 28 + d - 28]) +
                                  wy1 * bf2f(qraw[y1 * 28 + d - 28]));
                else v = 0.f;
                qv[e] = v;
            }
            union { unsigned u[2]; bf4 v; } cv;
            cv.u[0] = pk_bf16(qv[0], qv[1]);
            cv.u[1] = pk_bf16(qv[2], qv[3]);
            qf[kt] = cv.v;
        }
    }
    f4 Mv = *(const f4*)(P1M + b * 64 + 16 * w + 4 * g);
    __syncthreads();
    f4 acc[4];
#pragma unroll
    for (int nj = 0; nj < 4; ++nj)
        acc[nj] = *(const f4*)(P1T + (size_t)b * 4096 + (16 * nj + li) * 64 + 16 * w + 4 * g);
#pragma unroll
    for (int nj = 0; nj < 4; ++nj) {
        const unsigned short* kr = augK + (16 * nj + li) * 68 + 4 * g;
#pragma unroll
        for (int kt = 0; kt < 4; ++kt) {
            bf4 bk = *(const bf4*)(kr + 16 * kt);
            acc[nj] = mfma16(qf[kt], bk, acc[nj]);
        }
    }
    float lr[4] = {0.f, 0.f, 0.f, 0.f};
    unsigned short* Pww = Pw[w];
#pragma unroll
    for (int nj = 0; nj < 4; ++nj)
#pragma unroll
        for (int r = 0; r < 4; ++r) {
            float p = __expf(acc[nj][r] - Mv[r]);
            lr[r] += p;
            Pww[(4 * g + r) * 68 + 16 * nj + li] = f2bf(p);
        }
    f4 accv[2];
    accv[0] = (f4){0.f, 0.f, 0.f, 0.f};
    accv[1] = (f4){0.f, 0.f, 0.f, 0.f};
#pragma unroll
    for (int kt = 0; kt < 4; ++kt) {
        bf4 pa = *(const bf4*)(Pww + li * 68 + 16 * kt + 4 * g);
#pragma unroll
        for (int nc = 0; nc < 2; ++nc) {
            bf4 bv = *(const bf4*)(vT + (16 * nc + li) * 68 + 16 * kt + 4 * g);
            accv[nc] = mfma16(pa, bv, accv[nc]);
        }
    }
#pragma unroll
    for (int r = 0; r < 4; ++r) {
#pragma unroll
        for (int msk = 1; msk < 16; msk <<= 1) lr[r] += __shfl_xor(lr[r], msk);
        float invl = 1.0f / lr[r];
        int i = 16 * w + 4 * g + r;
        size_t wb = ((size_t)(b * 256 + n) * 64 + i) * 56;
        aout[wb + li] = f2bf(accv[0][r] * invl);
        if (li < 12) aout[wb + 16 + li] = f2bf(accv[1][r] * invl);
    }
}

// -------------------- K7: branch-2 cross-window attn, MFMA -----------------
__global__ __launch_bounds__(512) void k_attn2(const unsigned short* __restrict__ q2,
                                               const unsigned short* __restrict__ k2,
                                               const unsigned short* __restrict__ v2,
                                               const float* __restrict__ P2T,
                                               const float* __restrict__ P2M,
                                               const float* __restrict__ shif,
                                               unsigned short* __restrict__ aout) {
    extern __shared__ __align__(16) char smem[];
    unsigned short* augK = (unsigned short*)smem;                  // [256][68]
    unsigned short* vT = (unsigned short*)(smem + 34816);          // [28][260]
    int tid = threadIdx.x;
    int w = tid >> 6;
    int l = tid & 63;
    int g = l >> 4;
    int li = l & 15;
    unsigned short* Pw = (unsigned short*)(smem + 49376) + w * 1088;  // [16][68]
    int bm = blockIdx.x;
    int b = bm >> 6;
    int m = bm & 63;
    size_t gbase = (size_t)bm * 7168;
    float sx = shif[16 + b * 2 + 0];
    float sy = shif[16 + b * 2 + 1];
    if (tid < 256) {
        int j = tid;
        int x0, x1;
        float wx0, wx1;
        coords_(j, 256, sx, x0, x1, wx0, wx1);
        int rm = (j - 1) & 255;
        uint2* rowv = (uint2*)(augK + j * 68);
        const uint2* srcv = (const uint2*)(k2 + gbase + (size_t)rm * 28);
#pragma unroll
        for (int h = 0; h < 7; ++h) rowv[h] = srcv[h];
        const uint2* kav = (const uint2*)(k2 + gbase + (size_t)x0 * 28);
        const uint2* kbv = (const uint2*)(k2 + gbase + (size_t)x1 * 28);
        unsigned* row = (unsigned*)(augK + j * 68);
#pragma unroll
        for (int h = 0; h < 7; ++h) {
            uint2 va = kav[h], vb = kbv[h];
            float a0 = wx0 * bf2f((unsigned short)va.x) + wx1 * bf2f((unsigned short)vb.x);
            float a1 = wx0 * bf2f((unsigned short)(va.x >> 16)) +
                       wx1 * bf2f((unsigned short)(vb.x >> 16));
            float a2 = wx0 * bf2f((unsigned short)va.y) + wx1 * bf2f((unsigned short)vb.y);
            float a3 = wx0 * bf2f((unsigned short)(va.y >> 16)) +
                       wx1 * bf2f((unsigned short)(vb.y >> 16));
            row[14 + 2 * h] = pk_bf16(a0, a1);
            row[15 + 2 * h] = pk_bf16(a2, a3);
        }
#pragma unroll
        for (int h = 28; h < 34; ++h) row[h] = 0;
    } else {
        int j = tid - 256;
        const uint2* vrv = (const uint2*)(v2 + gbase + (size_t)j * 28);
#pragma unroll
        for (int h = 0; h < 7; ++h) {
            uint2 t = vrv[h];
            vT[(4 * h + 0) * 260 + j] = (unsigned short)t.x;
            vT[(4 * h + 1) * 260 + j] = (unsigned short)(t.x >> 16);
            vT[(4 * h + 2) * 260 + j] = (unsigned short)t.y;
            vT[(4 * h + 3) * 260 + j] = (unsigned short)(t.y >> 16);
        }
    }
    // ---- Q fragments via uint2 register loads (exact per-(kt,g) source map)
    bf4 qf[2][4];
#pragma unroll
    for (int mi = 0; mi < 2; ++mi) {
        int i = 32 * w + 16 * mi + li;
        int y0, y1;
        float wy0, wy1;
        coords_(i, 256, sy, y0, y1, wy0, wy1);
        int rm = (i - 1) & 255;
        const uint2* qrmv = (const uint2*)(q2 + gbase + (size_t)rm * 28);
        const uint2* qav = (const uint2*)(q2 + gbase + (size_t)y0 * 28);
        const uint2* qbv = (const uint2*)(q2 + gbase + (size_t)y1 * 28);
        {
            uint2 r0 = qrmv[g];
            qf[mi][0] = pack4(SCALE_ * bf2f((unsigned short)r0.x),
                              SCALE_ * bf2f((unsigned short)(r0.x >> 16)),
                              SCALE_ * bf2f((unsigned short)r0.y),
                              SCALE_ * bf2f((unsigned short)(r0.y >> 16)));
        }
        if (g < 3) {
            uint2 r1 = qrmv[4 + g];
            qf[mi][1] = pack4(SCALE_ * bf2f((unsigned short)r1.x),
                              SCALE_ * bf2f((unsigned short)(r1.x >> 16)),
                              SCALE_ * bf2f((unsigned short)r1.y),
                              SCALE_ * bf2f((unsigned short)(r1.y >> 16)));
        } else {
            uint2 a = qav[0], bb = qbv[0];
            qf[mi][1] = pack4(
                SCALE_ * (wy0 * bf2f((unsigned short)a.x) + wy1 * bf2f((unsigned short)bb.x)),
                SCALE_ * (wy0 * bf2f((unsigned short)(a.x >> 16)) +
                          wy1 * bf2f((unsigned short)(bb.x >> 16))),
                SCALE_ * (wy0 * bf2f((unsigned short)a.y) + wy1 * bf2f((unsigned short)bb.y)),
                SCALE_ * (wy0 * bf2f((unsigned short)(a.y >> 16)) +
                          wy1 * bf2f((unsigned short)(bb.y >> 16))));
        }
        {
            uint2 a = qav[1 + g], bb = qbv[1 + g];
            qf[mi][2] = pack4(
                SCALE_ * (wy0 * bf2f((unsigned short)a.x) + wy1 * bf2f((unsigned short)bb.x)),
                SCALE_ * (wy0 * bf2f((unsigned short)(a.x >> 16)) +
                          wy1 * bf2f((unsigned short)(bb.x >> 16))),
                SCALE_ * (wy0 * bf2f((unsigned short)a.y) + wy1 * bf2f((unsigned short)bb.y)),
                SCALE_ * (wy0 * bf2f((unsigned short)(a.y >> 16)) +
                          wy1 * bf2f((unsigned short)(bb.y >> 16))));
        }
        if (g < 2) {
            uint2 a = qav[5 + g], bb = qbv[5 + g];
            qf[mi][3] = pack4(
                SCALE_ * (wy0 * bf2f((unsigned short)a.x) + wy1 * bf2f((unsigned short)bb.x)),
                SCALE_ * (wy0 * bf2f((unsigned short)(a.x >> 16)) +
                          wy1 * bf2f((unsigned short)(bb.x >> 16))),
                SCALE_ * (wy0 * bf2f((unsigned short)a.y) + wy1 * bf2f((unsigned short)bb.y)),
                SCALE_ * (wy0 * bf2f((unsigned short)(a.y >> 16)) +
                          wy1 * bf2f((unsigned short)(bb.y >> 16))));
        } else {
            union { unsigned u[2]; bf4 v; } cz;
            cz.u[0] = 0;
            cz.u[1] = 0;
            qf[mi][3] = cz.v;
        }
    }
    float M[2][4];
#pragma unroll
    for (int mi = 0; mi < 2; ++mi)
#pragma unroll
        for (int r = 0; r < 4; ++r)
            M[mi][r] = P2M[b * 256 + 32 * w + 16 * mi + 4 * g + r];
    __syncthreads();
    f4 accv[2][2];
#pragma unroll
    for (int mi = 0; mi < 2; ++mi)
#pragma unroll
        for (int nc = 0; nc < 2; ++nc) accv[mi][nc] = (f4){0.f, 0.f, 0.f, 0.f};
    float lrun[2][4];
#pragma unroll
    for (int mi = 0; mi < 2; ++mi)
#pragma unroll
        for (int r = 0; r < 4; ++r) lrun[mi][r] = 0.f;

    for (int jt = 0; jt < 4; ++jt) {
#pragma unroll
        for (int mi = 0; mi < 2; ++mi) {
            f4 acc[4];
#pragma unroll
            for (int nj = 0; nj < 4; ++nj)
                acc[nj] = *(const f4*)(P2T + (size_t)b * 65536 +
                                       (size_t)(64 * jt + 16 * nj + li) * 256 +
                                       32 * w + 16 * mi + 4 * g);
#pragma unroll
            for (int nj = 0; nj < 4; ++nj) {
                const unsigned short* kr = augK + (64 * jt + 16 * nj + li) * 68 + 4 * g;
#pragma unroll
                for (int kt = 0; kt < 4; ++kt) {
                    bf4 bk = *(const bf4*)(kr + 16 * kt);
                    acc[nj] = mfma16(qf[mi][kt], bk, acc[nj]);
                }
            }
#pragma unroll
            for (int nj = 0; nj < 4; ++nj)
#pragma unroll
                for (int r = 0; r < 4; ++r) {
                    float p = __expf(acc[nj][r] - M[mi][r]);
                    lrun[mi][r] += p;
                    Pw[(4 * g + r) * 68 + 16 * nj + li] = f2bf(p);
                }
#pragma unroll
            for (int kt = 0; kt < 4; ++kt) {
                bf4 pa = *(const bf4*)(Pw + li * 68 + 16 * kt + 4 * g);
#pragma unroll
                for (int nc = 0; nc < 2; ++nc) {
                    bf4 bv = *(const bf4*)(vT + (16 * nc + li) * 260 + 64 * jt + 16 * kt + 4 * g);
                    accv[mi][nc] = mfma16(pa, bv, accv[mi][nc]);
                }
            }
        }
    }
#pragma unroll
    for (int mi = 0; mi < 2; ++mi)
#pragma unroll
        for (int r = 0; r < 4; ++r) {
#pragma unroll
            for (int msk = 1; msk < 16; msk <<= 1)
                lrun[mi][r] += __shfl_xor(lrun[mi][r], msk);
            float invl = 1.0f / lrun[mi][r];
            int gi = 32 * w + 16 * mi + 4 * g + r;
            size_t wb = (((size_t)b * 256 + gi) * 64 + m) * 56 + 28;
            aout[wb + li] = f2bf(accv[mi][0][r] * invl);
            if (li < 12) aout[wb + 16 + li] = f2bf(accv[mi][1][r] * invl);
        }
}

// ---------------- K8: output projection + unwindow (MFMA, prepped B) -------
__global__ __launch_bounds__(256) void k_out(const unsigned short* __restrict__ aout,
                                             const unsigned short* __restrict__ WFo,
                                             const float* __restrict__ bout,
                                             float* __restrict__ out) {
    __shared__ __align__(16) unsigned short Ah[64 * 68];
    __shared__ __align__(16) float st[64 * 60];
    int tid = threadIdx.x;
    int w = tid >> 6;
    int l = tid & 63;
    int g = l >> 4;
    int li = l & 15;
    int pix0 = blockIdx.x * 64;
    for (int e = tid; e < 896; e += 256) {
        int row = e / 14;
        int c4 = (e - row * 14) * 4;
        *(uint2*)(Ah + row * 68 + c4) = *(const uint2*)(aout + (size_t)pix0 * 56 + 4 * e);
    }
    for (int e = tid; e < 384; e += 256) {
        int row = e / 6;
        ((unsigned*)Ah)[row * 34 + 28 + (e - row * 6)] = 0;
    }
    bf4 Bo[4][4];
#pragma unroll
    for (int nt = 0; nt < 4; ++nt)
#pragma unroll
        for (int kt = 0; kt < 4; ++kt)
            Bo[nt][kt] = *(const bf4*)(WFo + ((nt * 4 + kt) * 64 + l) * 4);
    __syncthreads();
    f4 acc[4];
#pragma unroll
    for (int nt = 0; nt < 4; ++nt) acc[nt] = (f4){0.f, 0.f, 0.f, 0.f};
    bf4 ah[4];
#pragma unroll
    for (int kt = 0; kt < 4; ++kt)
        ah[kt] = *(const bf4*)(Ah + (16 * w + li) * 68 + 16 * kt + 4 * g);
#pragma unroll
    for (int nt = 0; nt < 4; ++nt)
#pragma unroll
        for (int kt = 0; kt < 4; ++kt)
            acc[nt] = mfma16(ah[kt], Bo[nt][kt], acc[nt]);
#pragma unroll
    for (int nt = 0; nt < 4; ++nt) {
        int col = 16 * nt + li;
        if (col < 56) {
#pragma unroll
            for (int r = 0; r < 4; ++r)
                st[(16 * w + 4 * g + r) * 60 + col] = acc[nt][r];
        }
    }
    __syncthreads();
    int row = tid >> 2;
    int qq = tid & 3;
    int pixel = pix0 + row;
    int b = pixel >> 14;
    int n = (pixel >> 6) & 255;
    int m = pixel & 63;
    int h = ((n >> 4) << 3) + (m >> 3);
    int ww = ((n & 15) << 3) + (m & 7);
    float* dst = out + (((size_t)b * 128 + h) * 128 + ww) * 56;
    const float* sr = st + row * 60;
#pragma unroll
    for (int cc = 0; cc < 14; cc += 2) {
        int c = 14 * qq + cc;
        float2 o;
        o.x = sr[c] + bout[c];
        o.y = sr[c + 1] + bout[c + 1];
        *(float2*)(dst + c) = o;
    }
}

// ---------------------------------------------------------------------------
extern "C" void kernel_launch(void* const* d_in, const int* in_sizes, int n_in,
                              void* d_out, int out_size, void* d_ws, size_t ws_size,
                              hipStream_t stream) {
    const float* x = (const float*)d_in[0];
    const float* pos1 = (const float*)d_in[1];
    const float* pos2 = (const float*)d_in[2];
    const float* Wq = (const float*)d_in[3];
    const float* Wkv = (const float*)d_in[4];
    const float* Wout = (const float*)d_in[5];
    const float* bout = (const float*)d_in[6];
    const float* c1w = (const float*)d_in[7];
    const float* c1b = (const float*)d_in[8];
    const float* c2w = (const float*)d_in[9];
    const float* c2b = (const float*)d_in[10];
    const float* f1w = (const float*)d_in[11];
    const float* f1b = (const float*)d_in[12];
    const float* f2w = (const float*)d_in[13];
    const float* f2b = (const float*)d_in[14];

    unsigned short* us = (unsigned short*)d_ws;
    unsigned short* q1 = us;
    unsigned short* k1 = us + 3670016;
    unsigned short* v1 = us + 7340032;
    unsigned short* q2 = us + 11010048;
    unsigned short* k2 = us + 14680064;
    unsigned short* v2 = us + 18350080;
    float* fb = (float*)d_ws + 11010048;
    unsigned short* ssb = (unsigned short*)fb;     // ssum bf16 [131072][56]
    unsigned short* aoutb = (unsigned short*)fb;   // aout bf16, overlays ssb
    unsigned short* c1o = (unsigned short*)(fb + 7340032);  // bf16 [16][16384][16]
    float* part = fb + 11534336;
    float* shif = fb + 11550720;
    float* P1T = fb + 11550752;
    float* P1M = fb + 11583520;
    float* P2R = fb + 11584032;
    float* P2M = fb + 12108320;
    unsigned short* WF = (unsigned short*)(fb + 12110368);
    unsigned short* WFo = WF + 11264;
    unsigned short* BF1 = WFo + 4096;   // 9216 u16 (hi 4608 | lo 4608)
    unsigned short* BF2 = BF1 + 9216;   // 4608 u16 (hi 2304 | lo 2304)
    float* P2T = (float*)(BF2 + 4608);  // [8][256][256] f32 (16B-aligned)
    float* outp = (float*)d_out;

    (void)hipFuncSetAttribute((const void*)k_qkv,
                              hipFuncAttributeMaxDynamicSharedMemorySize, 30720);
    (void)hipFuncSetAttribute((const void*)k_attn2,
                              hipFuncAttributeMaxDynamicSharedMemorySize, 66784);

    k_prep<<<87, 256, 0, stream>>>(Wq, Wkv, Wout, c1w, c2w, WF, WFo, BF1, BF2);
    k_qkv<<<2048, 256, 30720, stream>>>(x, WF, q1, k1, v1, q2, k2, v2, ssb);
    k_conv1<<<1024, 256, 0, stream>>>(ssb, BF1, c1b, c1o);
    k_conv2<<<1024, 256, 0, stream>>>(c1o, BF2, c2b, part);
    k_fc<<<1, 256, 0, stream>>>(part, f1w, f1b, f2w, f2b, shif);
    k_pos<<<2056, 256, 0, stream>>>(pos1, pos2, shif, P1T, P1M, P2R, P2M);
    k_posT<<<128, 256, 0, stream>>>(P2R, P2T);
    k_attn1<<<2048, 256, 0, stream>>>(q1, k1, v1, P1T, P1M, shif, aoutb);
    k_attn2<<<512, 512, 66784, stream>>>(q2, k2, v2, P2T, P2M, shif, aoutb);
    k_out<<<2048, 256, 0, stream>>>(aoutb, WFo, bout, outp);
}

// Round 17
// 134.981 us; speedup vs baseline: 6.1314x; 1.0095x over previous
//
#include <hip/hip_runtime.h>
#include <cstdint>

// ---------------------------------------------------------------------------
// SS-MSA fused implementation, round 17 (= round 15 + attn2 staging rebalance
// + k_out double-tile; the attn1/attn2 single-kernel fusion is abandoned:
// two independent implementations failed with identical absmax).
// grid_shift(sim) factorizes: shifted[i,j] = SCALE*(q_{i-1}.k_{j-1} + q~_i.k~_j) + P[i,j]
// => both branches are plain attention with 56-dim augmented Q/K + bias P.
//
// Round-17 changes vs round 15 (passing, 136.3us):
//  - k_attn2 staging rebalanced: lower 256 threads = plain K copy + pad,
//    upper 256 = K interp (same rows), V scatter split across all 512.
//    Same loads / pk_bf16 arithmetic / destinations; only thread->task map.
//  - k_out: two 64-pixel tiles per block (grid 1024), Bo loaded once,
//    loop-end barrier protects Ah/st reuse.
// ---------------------------------------------------------------------------

#define SCALE_ 0.18898223650461364f  // 28^-0.5

using f4 = __attribute__((ext_vector_type(4))) float;
using bf4 = __attribute__((ext_vector_type(4))) short;

__device__ __forceinline__ f4 mfma16(bf4 a, bf4 b, f4 c) {
#if __has_builtin(__builtin_amdgcn_mfma_f32_16x16x16bf16_1k)
    return __builtin_amdgcn_mfma_f32_16x16x16bf16_1k(a, b, c, 0, 0, 0);
#else
    f4 d;
    asm("v_mfma_f32_16x16x16_bf16 %0, %1, %2, %3" : "=v"(d) : "v"(a), "v"(b), "v"(c));
    return d;
#endif
}

__device__ __forceinline__ unsigned pk_bf16(float lo, float hi) {
    unsigned r;
    asm("v_cvt_pk_bf16_f32 %0, %1, %2" : "=v"(r) : "v"(lo), "v"(hi));
    return r;
}
__device__ __forceinline__ unsigned short f2bf(float f) {
    return (unsigned short)pk_bf16(f, f);
}
__device__ __forceinline__ float bf2f(unsigned short h) {
    return __uint_as_float(((unsigned)h) << 16);
}
__device__ __forceinline__ bf4 pack4(float a, float b, float c, float d) {
    union { unsigned u[2]; bf4 v; } cv;
    cv.u[0] = pk_bf16(a, b);
    cv.u[1] = pk_bf16(c, d);
    return cv.v;
}

__device__ __forceinline__ void coords_(int idx, int S, float s,
                                        int& i0, int& i1, float& w0, float& w1) {
    float g = -1.0f + 2.0f * (float)idx / (float)(S - 1);
    float c = (g + s * 2.0f / (float)S + 1.0f) * 0.5f * (float)(S - 1);
    float span = (float)(S - 1);
    c = fabsf(c);
    c = fmodf(c, 2.0f * span);
    if (c > span) c = 2.0f * span - c;
    int f = (int)floorf(c);
    f = max(0, min(f, S - 1));
    i0 = f;
    i1 = min(f + 1, S - 1);
    w1 = c - (float)f;
    w0 = 1.0f - w1;
}

// ------------------ K0: weight prep (fragment-ordered bf16) ----------------
__global__ __launch_bounds__(256) void k_prep(const float* __restrict__ Wq,
                                              const float* __restrict__ Wkv,
                                              const float* __restrict__ Wout,
                                              const float* __restrict__ c1w,
                                              const float* __restrict__ c2w,
                                              unsigned short* __restrict__ WF,
                                              unsigned short* __restrict__ WFo,
                                              unsigned short* __restrict__ BF1,
                                              unsigned short* __restrict__ BF2) {
    int tid = blockIdx.x * 256 + threadIdx.x;
    if (tid < 11264) {
        int e = tid & 3;
        int l = (tid >> 2) & 63;
        int kt = (tid >> 8) & 3;
        int nt = tid >> 10;
        int g = l >> 4, li = l & 15;
        int k = 16 * kt + 4 * g + e;
        int col = 16 * nt + li;
        float v = 0.f;
        if (k < 56 && col < 168)
            v = (col < 56) ? Wq[k * 56 + col] : Wkv[k * 112 + (col - 56)];
        WF[tid] = f2bf(v);
    } else if (tid < 15360) {
        int t2 = tid - 11264;
        int e = t2 & 3;
        int l = (t2 >> 2) & 63;
        int kt = (t2 >> 8) & 3;
        int nt = t2 >> 10;
        int g = l >> 4, li = l & 15;
        int k = 16 * kt + 4 * g + e;
        int col = 16 * nt + li;
        float v = (k < 56 && col < 56) ? Wout[k * 56 + col] : 0.f;
        WFo[t2] = f2bf(v);
    } else if (tid < 19968) {
        int t2 = tid - 15360;  // 4608 entries
        int e = t2 & 3;
        int l = (t2 >> 2) & 63;
        int rest = t2 >> 8;    // t*2+kg
        int kg = rest & 1;
        int t = rest >> 1;
        int g = l >> 4, li = l & 15;
        int c = 16 * kg + 4 * g + e;
        float v = (c < 28) ? c1w[li * 252 + c * 9 + t] : 0.f;
        unsigned short h = f2bf(v);
        BF1[t2] = h;
        BF1[4608 + t2] = f2bf(v - bf2f(h));
    } else if (tid < 22272) {
        int t2 = tid - 19968;  // 2304 entries
        int e = t2 & 3;
        int l = (t2 >> 2) & 63;
        int t = t2 >> 8;
        int g = l >> 4, li = l & 15;
        int c = 4 * g + e;
        float v = c2w[li * 144 + c * 9 + t];
        unsigned short h = f2bf(v);
        BF2[t2] = h;
        BF2[2304 + t2] = f2bf(v - bf2f(h));
    }
}

// ------------------- K1: QKV GEMM (bf16 MFMA, prepped B) -------------------
__global__ __launch_bounds__(256) void k_qkv(const float* __restrict__ x,
                                             const unsigned short* __restrict__ WF,
                                             unsigned short* __restrict__ q1,
                                             unsigned short* __restrict__ k1,
                                             unsigned short* __restrict__ v1,
                                             unsigned short* __restrict__ q2,
                                             unsigned short* __restrict__ k2,
                                             unsigned short* __restrict__ v2,
                                             unsigned short* __restrict__ ssum) {
    extern __shared__ __align__(16) char smem[];
    unsigned short* Ah = (unsigned short*)smem;            // [64][68]
    unsigned short* st = (unsigned short*)(smem + 8704);   // [64][172]
    int tid = threadIdx.x;
    int w = tid >> 6;
    int l = tid & 63;
    int g = l >> 4;
    int li = l & 15;
    int pix0 = blockIdx.x * 64;
    for (int e = tid; e < 896; e += 256) {
        int row = e / 14;
        int c4 = (e - row * 14) * 4;
        float4 v = *(const float4*)(x + (size_t)pix0 * 56 + 4 * e);
        uint2 p;
        p.x = pk_bf16(v.x, v.y);
        p.y = pk_bf16(v.z, v.w);
        *(uint2*)((unsigned*)Ah + row * 34 + (c4 >> 1)) = p;
    }
    for (int e = tid; e < 384; e += 256) {
        int row = e / 6;
        ((unsigned*)Ah)[row * 34 + 28 + (e - row * 6)] = 0;
    }
    int nt0 = 3 * w;
    int nnt = (w < 3) ? 3 : 2;
    bf4 B[3][4];
#pragma unroll
    for (int t = 0; t < 3; ++t) {
        if (t >= nnt) break;
#pragma unroll
        for (int kt = 0; kt < 4; ++kt)
            B[t][kt] = *(const bf4*)(WF + (((nt0 + t) * 4 + kt) * 64 + l) * 4);
    }
    __syncthreads();
    f4 acc[4][3];
#pragma unroll
    for (int mi = 0; mi < 4; ++mi)
#pragma unroll
        for (int t = 0; t < 3; ++t) acc[mi][t] = (f4){0.f, 0.f, 0.f, 0.f};
#pragma unroll
    for (int mi = 0; mi < 4; ++mi) {
        bf4 a[4];
#pragma unroll
        for (int kt = 0; kt < 4; ++kt)
            a[kt] = *(const bf4*)(Ah + (16 * mi + li) * 68 + 16 * kt + 4 * g);
#pragma unroll
        for (int t = 0; t < 3; ++t) {
            if (t >= nnt) break;
#pragma unroll
            for (int kt = 0; kt < 4; ++kt)
                acc[mi][t] = mfma16(a[kt], B[t][kt], acc[mi][t]);
        }
    }
#pragma unroll
    for (int mi = 0; mi < 4; ++mi)
#pragma unroll
        for (int t = 0; t < 3; ++t) {
            if (t >= nnt) break;
            int col = 16 * (nt0 + t) + li;
            if (col < 168) {
#pragma unroll
                for (int r = 0; r < 4; ++r)
                    st[(16 * mi + 4 * g + r) * 172 + col] = f2bf(acc[mi][t][r]);
            }
        }
    __syncthreads();
    {
        int row = tid >> 2;
        int qq = tid & 3;
        int pixel = pix0 + row;
        int b = pixel >> 14;
        int rem = pixel & 16383;
        int hh = rem >> 7;
        int ww = rem & 127;
        int n = ((hh >> 3) << 4) + (ww >> 3);
        int m = ((hh & 7) << 3) + (ww & 7);
        size_t ob = ((size_t)(b * 256 + n) * 64 + m) * 56 + 14 * qq;
        const unsigned short* sr = st + row * 172 + 14 * qq;
#pragma unroll
        for (int h = 0; h < 7; ++h) {
            unsigned qw = *(const unsigned*)(sr + 2 * h);
            unsigned kw = *(const unsigned*)(sr + 56 + 2 * h);
            unsigned vw = *(const unsigned*)(sr + 112 + 2 * h);
            float s0 = __uint_as_float(qw << 16) + __uint_as_float(kw << 16) +
                       __uint_as_float(vw << 16);
            float s1 = __uint_as_float(qw & 0xffff0000u) + __uint_as_float(kw & 0xffff0000u) +
                       __uint_as_float(vw & 0xffff0000u);
            *(unsigned*)(ssum + ob + 2 * h) = pk_bf16(s0, s1);
        }
    }
    for (int e = tid; e < 384; e += 256) {
        int row = e / 6;
        int half = e - row * 6;
        int pixel = pix0 + row;
        int b = pixel >> 14;
        int rem = pixel & 16383;
        int hh = rem >> 7;
        int ww = rem & 127;
        int n = ((hh >> 3) << 4) + (ww >> 3);
        int m = ((hh & 7) << 3) + (ww & 7);
        size_t p1 = ((size_t)(b * 256 + n) * 64 + m) * 28;
        size_t p2 = ((size_t)(b * 64 + m) * 256 + n) * 28;
        unsigned short* base =
            (half < 2) ? (half == 0 ? q1 + p1 : q2 + p2)
                       : (half < 4) ? (half == 2 ? k1 + p1 : k2 + p2)
                                    : (half == 4 ? v1 + p1 : v2 + p2);
        const unsigned short* src = st + row * 172 + half * 28;
#pragma unroll
        for (int h = 0; h < 7; ++h)
            *(uint2*)(base + 4 * h) = *(const uint2*)(src + 4 * h);
    }
}

// ---------------- K2: conv1, implicit-GEMM MFMA (bf16, hi/lo B) ------------
__global__ __launch_bounds__(256) void k_conv1(const unsigned short* __restrict__ ssum,
                                               const unsigned short* __restrict__ BF1,
                                               const float* __restrict__ c1b,
                                               unsigned short* __restrict__ c1o) {
    __shared__ __align__(16) unsigned short tile[6 * 66 * 36];
    int tid = threadIdx.x;
    int w = tid >> 6;
    int l = tid & 63;
    int g = l >> 4;
    int li = l & 15;
    int wg = blockIdx.x;
    int br = wg >> 9;
    int b = (wg >> 6) & 7;
    int nt = wg & 63;
    int n0 = nt * 4;
    for (int e = tid; e < 2772; e += 256) {
        int c4 = e % 7;
        int rest = e / 7;
        int mm = rest % 66;
        int nr = rest / 66;
        int n = n0 - 1 + nr;
        int m = mm - 1;
        uint2 v = make_uint2(0u, 0u);
        if (n >= 0 && n < 256 && m >= 0 && m < 64)
            v = *(const uint2*)(ssum + (((size_t)b * 256 + n) * 64 + m) * 56 + br * 28 + 4 * c4);
        *(uint2*)(tile + (nr * 66 + mm) * 36 + 4 * c4) = v;
    }
    for (int e = tid; e < 396; e += 256)
        *(uint2*)(tile + e * 36 + 28) = make_uint2(0u, 0u);
    bf4 Bh[9][2], Bl[9][2];
#pragma unroll
    for (int t = 0; t < 9; ++t)
#pragma unroll
        for (int kg = 0; kg < 2; ++kg) {
            Bh[t][kg] = *(const bf4*)(BF1 + ((t * 2 + kg) * 64 + l) * 4);
            Bl[t][kg] = *(const bf4*)(BF1 + 4608 + ((t * 2 + kg) * 64 + l) * 4);
        }
    __syncthreads();
    f4 acc[4];
#pragma unroll
    for (int mt = 0; mt < 4; ++mt) acc[mt] = (f4){0.f, 0.f, 0.f, 0.f};
#pragma unroll
    for (int mt = 0; mt < 4; ++mt) {
#pragma unroll
        for (int t = 0; t < 9; ++t) {
            int ky = t / 3, kx = t - 3 * (t / 3);
#pragma unroll
            for (int kg = 0; kg < 2; ++kg) {
                bf4 a = *(const bf4*)(tile + ((w + ky) * 66 + 16 * mt + li + kx) * 36 +
                                      16 * kg + 4 * g);
                acc[mt] = mfma16(a, Bh[t][kg], acc[mt]);
                acc[mt] = mfma16(a, Bl[t][kg], acc[mt]);
            }
        }
    }
    float bias = c1b[li];
    size_t combo = (size_t)(br * 8 + b);
#pragma unroll
    for (int mt = 0; mt < 4; ++mt)
#pragma unroll
        for (int r = 0; r < 4; ++r) {
            int m = 16 * mt + 4 * g + r;
            float v = fmaxf(acc[mt][r] + bias, 0.f);
            c1o[(combo * 16384 + (size_t)(n0 + w) * 64 + m) * 16 + li] = f2bf(v);
        }
}

// ------------- K3: conv2 + pooled partials, implicit-GEMM MFMA -------------
__global__ __launch_bounds__(256) void k_conv2(const unsigned short* __restrict__ c1o,
                                               const unsigned short* __restrict__ BF2,
                                               const float* __restrict__ c2b,
                                               float* __restrict__ part) {
    __shared__ __align__(16) unsigned short tile[6 * 66 * 20];
    __shared__ float pbuf[4][16];
    int tid = threadIdx.x;
    int w = tid >> 6;
    int l = tid & 63;
    int g = l >> 4;
    int li = l & 15;
    int wg = blockIdx.x;
    int br = wg >> 9;
    int b = (wg >> 6) & 7;
    int nt = wg & 63;
    int n0 = nt * 4;
    size_t combo = (size_t)(br * 8 + b);
    for (int e = tid; e < 1584; e += 256) {
        int c4 = e & 3;
        int rest = e >> 2;
        int mm = rest % 66;
        int nr = rest / 66;
        int n = n0 - 1 + nr;
        int m = mm - 1;
        uint2 v = make_uint2(0u, 0u);
        if (n >= 0 && n < 256 && m >= 0 && m < 64)
            v = *(const uint2*)(c1o + (combo * 16384 + (size_t)n * 64 + m) * 16 + 4 * c4);
        *(uint2*)(tile + (nr * 66 + mm) * 20 + 4 * c4) = v;
    }
    bf4 Bh[9], Bl[9];
#pragma unroll
    for (int t = 0; t < 9; ++t) {
        Bh[t] = *(const bf4*)(BF2 + (t * 64 + l) * 4);
        Bl[t] = *(const bf4*)(BF2 + 2304 + (t * 64 + l) * 4);
    }
    __syncthreads();
    f4 acc[4];
#pragma unroll
    for (int mt = 0; mt < 4; ++mt) acc[mt] = (f4){0.f, 0.f, 0.f, 0.f};
#pragma unroll
    for (int mt = 0; mt < 4; ++mt) {
#pragma unroll
        for (int t = 0; t < 9; ++t) {
            int ky = t / 3, kx = t - 3 * (t / 3);
            bf4 a = *(const bf4*)(tile + ((w + ky) * 66 + 16 * mt + li + kx) * 20 + 4 * g);
            acc[mt] = mfma16(a, Bh[t], acc[mt]);
            acc[mt] = mfma16(a, Bl[t], acc[mt]);
        }
    }
    float bias = c2b[li];
    float s = 0.f;
#pragma unroll
    for (int mt = 0; mt < 4; ++mt)
#pragma unroll
        for (int r = 0; r < 4; ++r) s += fmaxf(acc[mt][r] + bias, 0.f);
    s += __shfl_xor(s, 16);
    s += __shfl_xor(s, 32);
    if (l < 16) pbuf[w][li] = s;
    __syncthreads();
    if (tid < 16) {
        float tot = pbuf[0][tid] + pbuf[1][tid] + pbuf[2][tid] + pbuf[3][tid];
        part[(combo * 64 + nt) * 16 + tid] = tot;
    }
}

// ------------------------- K4: reduce + FC -> shifts -----------------------
__global__ void k_fc(const float* __restrict__ part, const float* __restrict__ f1w,
                     const float* __restrict__ f1b, const float* __restrict__ f2w,
                     const float* __restrict__ f2b, float* __restrict__ shif) {
    __shared__ float sb[16][16];
    int t = threadIdx.x;
    int combo = t >> 4;
    int o = t & 15;
    float s = 0.f;
    for (int nt = 0; nt < 64; ++nt) s += part[((size_t)combo * 64 + nt) * 16 + o];
    sb[combo][o] = s * (1.0f / 16384.0f);
    __syncthreads();
    if (t < 16) {
        float p0 = f1b[0], p1 = f1b[1], rg = f2b[0];
        for (int oo = 0; oo < 16; ++oo) {
            float sv = sb[t][oo];
            p0 += sv * f1w[oo * 2 + 0];
            p1 += sv * f1w[oo * 2 + 1];
            rg += sv * f2w[oo];
        }
        shif[t * 2 + 0] = rg * tanhf(p0);
        shif[t * 2 + 1] = rg * tanhf(p1);
    }
}

// ----------------- K5: shifted pos precompute (pos2 | pos1) ----------------
__global__ __launch_bounds__(256) void k_pos(const float* __restrict__ pos1,
                                             const float* __restrict__ pos2,
                                             const float* __restrict__ shif,
                                             float* __restrict__ P1T,
                                             float* __restrict__ P1M,
                                             float* __restrict__ P2R,
                                             float* __restrict__ P2M) {
    __shared__ float plds[64 * 64];
    if (blockIdx.x < 2048) {
        int wg = blockIdx.x;
        int b = wg >> 8;
        int i = wg & 255;
        float sx = shif[16 + b * 2 + 0];
        float sy = shif[16 + b * 2 + 1];
        int j = threadIdx.x;
        int y0, y1, x0, x1;
        float wy0, wy1, wx0, wx1;
        coords_(i, 256, sy, y0, y1, wy0, wy1);
        coords_(j, 256, sx, x0, x1, wx0, wx1);
        float v = pos2[((i - 1) & 255) * 256 + ((j - 1) & 255)] +
                  wy0 * (wx0 * pos2[y0 * 256 + x0] + wx1 * pos2[y0 * 256 + x1]) +
                  wy1 * (wx0 * pos2[y1 * 256 + x0] + wx1 * pos2[y1 * 256 + x1]);
        P2R[(size_t)b * 65536 + (size_t)i * 256 + j] = v;
        float mx = v;
#pragma unroll
        for (int msk = 1; msk < 64; msk <<= 1) mx = fmaxf(mx, __shfl_xor(mx, msk));
        if ((threadIdx.x & 63) == 0) plds[threadIdx.x >> 6] = mx;
        __syncthreads();
        if (threadIdx.x == 0)
            P2M[b * 256 + i] = fmaxf(fmaxf(plds[0], plds[1]), fmaxf(plds[2], plds[3]));
    } else {
        int b = blockIdx.x - 2048;
        float sx = shif[b * 2 + 0];
        float sy = shif[b * 2 + 1];
        for (int e = threadIdx.x; e < 4096; e += 256) {
            int j = e >> 6;
            int i = e & 63;
            int y0, y1, x0, x1;
            float wy0, wy1, wx0, wx1;
            coords_(i, 64, sy, y0, y1, wy0, wy1);
            coords_(j, 64, sx, x0, x1, wx0, wx1);
            float v = pos1[((i - 1) & 63) * 64 + ((j - 1) & 63)] +
                      wy0 * (wx0 * pos1[y0 * 64 + x0] + wx1 * pos1[y0 * 64 + x1]) +
                      wy1 * (wx0 * pos1[y1 * 64 + x0] + wx1 * pos1[y1 * 64 + x1]);
            P1T[(size_t)b * 4096 + j * 64 + i] = v;
            plds[j * 64 + i] = v;
        }
        __syncthreads();
        if (threadIdx.x < 64) {
            float mx = plds[threadIdx.x];
            for (int j = 1; j < 64; ++j) mx = fmaxf(mx, plds[j * 64 + threadIdx.x]);
            P1M[b * 64 + threadIdx.x] = mx;
        }
    }
}

// ---------------- K5c: transpose P2R -> P2T[b][j][i] (64x64 tiles) ---------
__global__ __launch_bounds__(256) void k_posT(const float* __restrict__ P2R,
                                              float* __restrict__ P2T) {
    __shared__ float t[64][65];
    int blk = blockIdx.x;     // 128 = 8 b x 16 tiles
    int b = blk >> 4;
    int t4 = blk & 15;
    int i0 = (t4 >> 2) * 64;
    int j0 = (t4 & 3) * 64;
    int tr = threadIdx.x >> 6;
    int tc = threadIdx.x & 63;
    for (int rr = 0; rr < 64; rr += 4)
        t[rr + tr][tc] = P2R[(size_t)b * 65536 + (size_t)(i0 + rr + tr) * 256 + j0 + tc];
    __syncthreads();
    for (int rr = 0; rr < 64; rr += 4)
        P2T[(size_t)b * 65536 + (size_t)(j0 + rr + tr) * 256 + i0 + tc] = t[tc][rr + tr];
}

// --------------- K6: branch-1 window attention (64x64), MFMA ---------------
__global__ __launch_bounds__(256) void k_attn1(const unsigned short* __restrict__ q1,
                                               const unsigned short* __restrict__ k1,
                                               const unsigned short* __restrict__ v1,
                                               const float* __restrict__ P1T,
                                               const float* __restrict__ P1M,
                                               const float* __restrict__ shif,
                                               unsigned short* __restrict__ aout) {
    __shared__ __align__(16) unsigned short qraw[64 * 28];
    __shared__ __align__(16) unsigned short kraw[64 * 28];
    __shared__ __align__(16) unsigned short augK[64 * 68];
    __shared__ __align__(16) unsigned short vT[32 * 68];
    __shared__ __align__(16) unsigned short Pw[4][16 * 68];
    int tid = threadIdx.x;
    int w = tid >> 6;
    int l = tid & 63;
    int g = l >> 4;
    int li = l & 15;
    int wg = blockIdx.x;
    int b = wg >> 8;
    int n = wg & 255;
    size_t gb = (size_t)(b * 256 + n) * 1792;
    float sx = shif[b * 2 + 0];
    float sy = shif[b * 2 + 1];
    for (int e = tid; e < 448; e += 256) {
        *(uint2*)(qraw + 4 * e) = *(const uint2*)(q1 + gb + 4 * e);
        *(uint2*)(kraw + 4 * e) = *(const uint2*)(k1 + gb + 4 * e);
        uint2 t = *(const uint2*)(v1 + gb + 4 * e);
        int idx = 4 * e;
        int j0 = idx / 28, c0 = idx - 28 * j0;
        int j1 = (idx + 1) / 28, c1 = (idx + 1) - 28 * j1;
        int j2 = (idx + 2) / 28, c2 = (idx + 2) - 28 * j2;
        int j3 = (idx + 3) / 28, c3 = (idx + 3) - 28 * j3;
        vT[c0 * 68 + j0] = (unsigned short)t.x;
        vT[c1 * 68 + j1] = (unsigned short)(t.x >> 16);
        vT[c2 * 68 + j2] = (unsigned short)t.y;
        vT[c3 * 68 + j3] = (unsigned short)(t.y >> 16);
    }
    for (int e = tid; e < 272; e += 256) vT[28 * 68 + e] = 0;
    __syncthreads();
    if (tid < 64) {
        int j = tid;
        int x0, x1;
        float wx0, wx1;
        coords_(j, 64, sx, x0, x1, wx0, wx1);
        int rm = (j - 1) & 63;
        uint2* rowv = (uint2*)(augK + j * 68);
        const uint2* srcv = (const uint2*)(kraw + rm * 28);
#pragma unroll
        for (int h = 0; h < 7; ++h) rowv[h] = srcv[h];
        unsigned* row = (unsigned*)(augK + j * 68);
#pragma unroll
        for (int h = 0; h < 14; ++h) {
            float a0 = wx0 * bf2f(kraw[x0 * 28 + 2 * h]) + wx1 * bf2f(kraw[x1 * 28 + 2 * h]);
            float a1 = wx0 * bf2f(kraw[x0 * 28 + 2 * h + 1]) + wx1 * bf2f(kraw[x1 * 28 + 2 * h + 1]);
            row[14 + h] = pk_bf16(a0, a1);
        }
#pragma unroll
        for (int h = 28; h < 34; ++h) row[h] = 0;
    }
    bf4 qf[4];
    {
        int i = 16 * w + li;
        int y0, y1;
        float wy0, wy1;
        coords_(i, 64, sy, y0, y1, wy0, wy1);
        int rm = (i - 1) & 63;
#pragma unroll
        for (int kt = 0; kt < 4; ++kt) {
            float qv[4];
#pragma unroll
            for (int e = 0; e < 4; ++e) {
                int d = 16 * kt + 4 * g + e;
                float v;
                if (d < 28) v = SCALE_ * bf2f(qraw[rm * 28 + d]);
                else if (d < 56)
                    v = SCALE_ * (wy0 * bf2f(qraw[y0 * 28 + d - 28]) +
                                  wy1 * bf2f(qraw[y1 * 28 + d - 28]));
                else v = 0.f;
                qv[e] = v;
            }
            union { unsigned u[2]; bf4 v; } cv;
            cv.u[0] = pk_bf16(qv[0], qv[1]);
            cv.u[1] = pk_bf16(qv[2], qv[3]);
            qf[kt] = cv.v;
        }
    }
    f4 Mv = *(const f4*)(P1M + b * 64 + 16 * w + 4 * g);
    __syncthreads();
    f4 acc[4];
#pragma unroll
    for (int nj = 0; nj < 4; ++nj)
        acc[nj] = *(const f4*)(P1T + (size_t)b * 4096 + (16 * nj + li) * 64 + 16 * w + 4 * g);
#pragma unroll
    for (int nj = 0; nj < 4; ++nj) {
        const unsigned short* kr = augK + (16 * nj + li) * 68 + 4 * g;
#pragma unroll
        for (int kt = 0; kt < 4; ++kt) {
            bf4 bk = *(const bf4*)(kr + 16 * kt);
            acc[nj] = mfma16(qf[kt], bk, acc[nj]);
        }
    }
    float lr[4] = {0.f, 0.f, 0.f, 0.f};
    unsigned short* Pww = Pw[w];
#pragma unroll
    for (int nj = 0; nj < 4; ++nj)
#pragma unroll
        for (int r = 0; r < 4; ++r) {
            float p = __expf(acc[nj][r] - Mv[r]);
            lr[r] += p;
            Pww[(4 * g + r) * 68 + 16 * nj + li] = f2bf(p);
        }
    f4 accv[2];
    accv[0] = (f4){0.f, 0.f, 0.f, 0.f};
    accv[1] = (f4){0.f, 0.f, 0.f, 0.f};
#pragma unroll
    for (int kt = 0; kt < 4; ++kt) {
        bf4 pa = *(const bf4*)(Pww + li * 68 + 16 * kt + 4 * g);
#pragma unroll
        for (int nc = 0; nc < 2; ++nc) {
            bf4 bv = *(const bf4*)(vT + (16 * nc + li) * 68 + 16 * kt + 4 * g);
            accv[nc] = mfma16(pa, bv, accv[nc]);
        }
    }
#pragma unroll
    for (int r = 0; r < 4; ++r) {
#pragma unroll
        for (int msk = 1; msk < 16; msk <<= 1) lr[r] += __shfl_xor(lr[r], msk);
        float invl = 1.0f / lr[r];
        int i = 16 * w + 4 * g + r;
        size_t wb = ((size_t)(b * 256 + n) * 64 + i) * 56;
        aout[wb + li] = f2bf(accv[0][r] * invl);
        if (li < 12) aout[wb + 16 + li] = f2bf(accv[1][r] * invl);
    }
}

// -------------------- K7: branch-2 cross-window attn, MFMA -----------------
// Staging rebalanced: lower 256 threads = plain K copy + pad for row tid&255;
// upper 256 = K interp for the same row; V scatter split across all 512.
__global__ __launch_bounds__(512) void k_attn2(const unsigned short* __restrict__ q2,
                                               const unsigned short* __restrict__ k2,
                                               const unsigned short* __restrict__ v2,
                                               const float* __restrict__ P2T,
                                               const float* __restrict__ P2M,
                                               const float* __restrict__ shif,
                                               unsigned short* __restrict__ aout) {
    extern __shared__ __align__(16) char smem[];
    unsigned short* augK = (unsigned short*)smem;                  // [256][68]
    unsigned short* vT = (unsigned short*)(smem + 34816);          // [28][260]
    int tid = threadIdx.x;
    int w = tid >> 6;
    int l = tid & 63;
    int g = l >> 4;
    int li = l & 15;
    unsigned short* Pw = (unsigned short*)(smem + 49376) + w * 1088;  // [16][68]
    int bm = blockIdx.x;
    int b = bm >> 6;
    int m = bm & 63;
    size_t gbase = (size_t)bm * 7168;
    float sx = shif[16 + b * 2 + 0];
    float sy = shif[16 + b * 2 + 1];
    {
        int j = tid & 255;
        if (tid < 256) {
            // plain K copy (cols 0..27) + zero pad (cols 56..67)
            int rm = (j - 1) & 255;
            uint2* rowv = (uint2*)(augK + j * 68);
            const uint2* srcv = (const uint2*)(k2 + gbase + (size_t)rm * 28);
#pragma unroll
            for (int h = 0; h < 7; ++h) rowv[h] = srcv[h];
            unsigned* row = (unsigned*)(augK + j * 68);
#pragma unroll
            for (int h = 28; h < 34; ++h) row[h] = 0;
        } else {
            // K interp (cols 28..55)
            int x0, x1;
            float wx0, wx1;
            coords_(j, 256, sx, x0, x1, wx0, wx1);
            const uint2* kav = (const uint2*)(k2 + gbase + (size_t)x0 * 28);
            const uint2* kbv = (const uint2*)(k2 + gbase + (size_t)x1 * 28);
            unsigned* row = (unsigned*)(augK + j * 68);
#pragma unroll
            for (int h = 0; h < 7; ++h) {
                uint2 va = kav[h], vb = kbv[h];
                float a0 = wx0 * bf2f((unsigned short)va.x) + wx1 * bf2f((unsigned short)vb.x);
                float a1 = wx0 * bf2f((unsigned short)(va.x >> 16)) +
                           wx1 * bf2f((unsigned short)(vb.x >> 16));
                float a2 = wx0 * bf2f((unsigned short)va.y) + wx1 * bf2f((unsigned short)vb.y);
                float a3 = wx0 * bf2f((unsigned short)(va.y >> 16)) +
                           wx1 * bf2f((unsigned short)(vb.y >> 16));
                row[14 + 2 * h] = pk_bf16(a0, a1);
                row[15 + 2 * h] = pk_bf16(a2, a3);
            }
        }
        // V scatter: all 512 threads, 1792 uint2 tasks
        for (int e = tid; e < 1792; e += 512) {
            int jv = e / 7;
            int c7 = e - 7 * jv;
            uint2 t = *(const uint2*)(v2 + gbase + (size_t)jv * 28 + 4 * c7);
            int c0 = 4 * c7;
            vT[(c0 + 0) * 260 + jv] = (unsigned short)t.x;
            vT[(c0 + 1) * 260 + jv] = (unsigned short)(t.x >> 16);
            vT[(c0 + 2) * 260 + jv] = (unsigned short)t.y;
            vT[(c0 + 3) * 260 + jv] = (unsigned short)(t.y >> 16);
        }
    }
    // ---- Q fragments via uint2 register loads (exact per-(kt,g) source map)
    bf4 qf[2][4];
#pragma unroll
    for (int mi = 0; mi < 2; ++mi) {
        int i = 32 * w + 16 * mi + li;
        int y0, y1;
        float wy0, wy1;
        coords_(i, 256, sy, y0, y1, wy0, wy1);
        int rm = (i - 1) & 255;
        const uint2* qrmv = (const uint2*)(q2 + gbase + (size_t)rm * 28);
        const uint2* qav = (const uint2*)(q2 + gbase + (size_t)y0 * 28);
        const uint2* qbv = (const uint2*)(q2 + gbase + (size_t)y1 * 28);
        {
            uint2 r0 = qrmv[g];
            qf[mi][0] = pack4(SCALE_ * bf2f((unsigned short)r0.x),
                              SCALE_ * bf2f((unsigned short)(r0.x >> 16)),
                              SCALE_ * bf2f((unsigned short)r0.y),
                              SCALE_ * bf2f((unsigned short)(r0.y >> 16)));
        }
        if (g < 3) {
            uint2 r1 = qrmv[4 + g];
            qf[mi][1] = pack4(SCALE_ * bf2f((unsigned short)r1.x),
                              SCALE_ * bf2f((unsigned short)(r1.x >> 16)),
                              SCALE_ * bf2f((unsigned short)r1.y),
                              SCALE_ * bf2f((unsigned short)(r1.y >> 16)));
        } else {
            uint2 a = qav[0], bb = qbv[0];
            qf[mi][1] = pack4(
                SCALE_ * (wy0 * bf2f((unsigned short)a.x) + wy1 * bf2f((unsigned short)bb.x)),
                SCALE_ * (wy0 * bf2f((unsigned short)(a.x >> 16)) +
                          wy1 * bf2f((unsigned short)(bb.x >> 16))),
                SCALE_ * (wy0 * bf2f((unsigned short)a.y) + wy1 * bf2f((unsigned short)bb.y)),
                SCALE_ * (wy0 * bf2f((unsigned short)(a.y >> 16)) +
                          wy1 * bf2f((unsigned short)(bb.y >> 16))));
        }
        {
            uint2 a = qav[1 + g], bb = qbv[1 + g];
            qf[mi][2] = pack4(
                SCALE_ * (wy0 * bf2f((unsigned short)a.x) + wy1 * bf2f((unsigned short)bb.x)),
                SCALE_ * (wy0 * bf2f((unsigned short)(a.x >> 16)) +
                          wy1 * bf2f((unsigned short)(bb.x >> 16))),
                SCALE_ * (wy0 * bf2f((unsigned short)a.y) + wy1 * bf2f((unsigned short)bb.y)),
                SCALE_ * (wy0 * bf2f((unsigned short)(a.y >> 16)) +
                          wy1 * bf2f((unsigned short)(bb.y >> 16))));
        }
        if (g < 2) {
            uint2 a = qav[5 + g], bb = qbv[5 + g];
            qf[mi][3] = pack4(
                SCALE_ * (wy0 * bf2f((unsigned short)a.x) + wy1 * bf2f((unsigned short)bb.x)),
                SCALE_ * (wy0 * bf2f((unsigned short)(a.x >> 16)) +
                          wy1 * bf2f((unsigned short)(bb.x >> 16))),
                SCALE_ * (wy0 * bf2f((unsigned short)a.y) + wy1 * bf2f((unsigned short)bb.y)),
                SCALE_ * (wy0 * bf2f((unsigned short)(a.y >> 16)) +
                          wy1 * bf2f((unsigned short)(bb.y >> 16))));
        } else {
            union { unsigned u[2]; bf4 v; } cz;
            cz.u[0] = 0;
            cz.u[1] = 0;
            qf[mi][3] = cz.v;
        }
    }
    float M[2][4];
#pragma unroll
    for (int mi = 0; mi < 2; ++mi)
#pragma unroll
        for (int r = 0; r < 4; ++r)
            M[mi][r] = P2M[b * 256 + 32 * w + 16 * mi + 4 * g + r];
    __syncthreads();
    f4 accv[2][2];
#pragma unroll
    for (int mi = 0; mi < 2; ++mi)
#pragma unroll
        for (int nc = 0; nc < 2; ++nc) accv[mi][nc] = (f4){0.f, 0.f, 0.f, 0.f};
    float lrun[2][4];
#pragma unroll
    for (int mi = 0; mi < 2; ++mi)
#pragma unroll
        for (int r = 0; r < 4; ++r) lrun[mi][r] = 0.f;

    for (int jt = 0; jt < 4; ++jt) {
#pragma unroll
        for (int mi = 0; mi < 2; ++mi) {
            f4 acc[4];
#pragma unroll
            for (int nj = 0; nj < 4; ++nj)
                acc[nj] = *(const f4*)(P2T + (size_t)b * 65536 +
                                       (size_t)(64 * jt + 16 * nj + li) * 256 +
                                       32 * w + 16 * mi + 4 * g);
#pragma unroll
            for (int nj = 0; nj < 4; ++nj) {
                const unsigned short* kr = augK + (64 * jt + 16 * nj + li) * 68 + 4 * g;
#pragma unroll
                for (int kt = 0; kt < 4; ++kt) {
                    bf4 bk = *(const bf4*)(kr + 16 * kt);
                    acc[nj] = mfma16(qf[mi][kt], bk, acc[nj]);
                }
            }
#pragma unroll
            for (int nj = 0; nj < 4; ++nj)
#pragma unroll
                for (int r = 0; r < 4; ++r) {
                    float p = __expf(acc[nj][r] - M[mi][r]);
                    lrun[mi][r] += p;
                    Pw[(4 * g + r) * 68 + 16 * nj + li] = f2bf(p);
                }
#pragma unroll
            for (int kt = 0; kt < 4; ++kt) {
                bf4 pa = *(const bf4*)(Pw + li * 68 + 16 * kt + 4 * g);
#pragma unroll
                for (int nc = 0; nc < 2; ++nc) {
                    bf4 bv = *(const bf4*)(vT + (16 * nc + li) * 260 + 64 * jt + 16 * kt + 4 * g);
                    accv[mi][nc] = mfma16(pa, bv, accv[mi][nc]);
                }
            }
        }
    }
#pragma unroll
    for (int mi = 0; mi < 2; ++mi)
#pragma unroll
        for (int r = 0; r < 4; ++r) {
#pragma unroll
            for (int msk = 1; msk < 16; msk <<= 1)
                lrun[mi][r] += __shfl_xor(lrun[mi][r], msk);
            float invl = 1.0f / lrun[mi][r];
            int gi = 32 * w + 16 * mi + 4 * g + r;
            size_t wb = (((size_t)b * 256 + gi) * 64 + m) * 56 + 28;
            aout[wb + li] = f2bf(accv[mi][0][r] * invl);
            if (li < 12) aout[wb + 16 + li] = f2bf(accv[mi][1][r] * invl);
        }
}

// -------- K8: output projection + unwindow (MFMA, prepped B, 2 tiles) ------
__global__ __launch_bounds__(256) void k_out(const unsigned short* __restrict__ aout,
                                             const unsigned short* __restrict__ WFo,
                                             const float* __restrict__ bout,
                                             float* __restrict__ out) {
    __shared__ __align__(16) unsigned short Ah[64 * 68];
    __shared__ __align__(16) float st[64 * 60];
    int tid = threadIdx.x;
    int w = tid >> 6;
    int l = tid & 63;
    int g = l >> 4;
    int li = l & 15;
    bf4 Bo[4][4];
#pragma unroll
    for (int nt = 0; nt < 4; ++nt)
#pragma unroll
        for (int kt = 0; kt < 4; ++kt)
            Bo[nt][kt] = *(const bf4*)(WFo + ((nt * 4 + kt) * 64 + l) * 4);
    for (int t = 0; t < 2; ++t) {
        int pix0 = (blockIdx.x * 2 + t) * 64;
        for (int e = tid; e < 896; e += 256) {
            int row = e / 14;
            int c4 = (e - row * 14) * 4;
            *(uint2*)(Ah + row * 68 + c4) = *(const uint2*)(aout + (size_t)pix0 * 56 + 4 * e);
        }
        for (int e = tid; e < 384; e += 256) {
            int row = e / 6;
            ((unsigned*)Ah)[row * 34 + 28 + (e - row * 6)] = 0;
        }
        __syncthreads();
        f4 acc[4];
#pragma unroll
        for (int nt = 0; nt < 4; ++nt) acc[nt] = (f4){0.f, 0.f, 0.f, 0.f};
        bf4 ah[4];
#pragma unroll
        for (int kt = 0; kt < 4; ++kt)
            ah[kt] = *(const bf4*)(Ah + (16 * w + li) * 68 + 16 * kt + 4 * g);
#pragma unroll
        for (int nt = 0; nt < 4; ++nt)
#pragma unroll
            for (int kt = 0; kt < 4; ++kt)
                acc[nt] = mfma16(ah[kt], Bo[nt][kt], acc[nt]);
#pragma unroll
        for (int nt = 0; nt < 4; ++nt) {
            int col = 16 * nt + li;
            if (col < 56) {
#pragma unroll
                for (int r = 0; r < 4; ++r)
                    st[(16 * w + 4 * g + r) * 60 + col] = acc[nt][r];
            }
        }
        __syncthreads();
        {
            int row = tid >> 2;
            int qq = tid & 3;
            int pixel = pix0 + row;
            int b = pixel >> 14;
            int n = (pixel >> 6) & 255;
            int m = pixel & 63;
            int h = ((n >> 4) << 3) + (m >> 3);
            int ww = ((n & 15) << 3) + (m & 7);
            float* dst = out + (((size_t)b * 128 + h) * 128 + ww) * 56;
            const float* sr = st + row * 60;
#pragma unroll
            for (int cc = 0; cc < 14; cc += 2) {
                int c = 14 * qq + cc;
                float2 o;
                o.x = sr[c] + bout[c];
                o.y = sr[c + 1] + bout[c + 1];
                *(float2*)(dst + c) = o;
            }
        }
        __syncthreads();
    }
}

// ---------------------------------------------------------------------------
extern "C" void kernel_launch(void* const* d_in, const int* in_sizes, int n_in,
                              void* d_out, int out_size, void* d_ws, size_t ws_size,
                              hipStream_t stream) {
    const float* x = (const float*)d_in[0];
    const float* pos1 = (const float*)d_in[1];
    const float* pos2 = (const float*)d_in[2];
    const float* Wq = (const float*)d_in[3];
    const float* Wkv = (const float*)d_in[4];
    const float* Wout = (const float*)d_in[5];
    const float* bout = (const float*)d_in[6];
    const float* c1w = (const float*)d_in[7];
    const float* c1b = (const float*)d_in[8];
    const float* c2w = (const float*)d_in[9];
    const float* c2b = (const float*)d_in[10];
    const float* f1w = (const float*)d_in[11];
    const float* f1b = (const float*)d_in[12];
    const float* f2w = (const float*)d_in[13];
    const float* f2b = (const float*)d_in[14];

    unsigned short* us = (unsigned short*)d_ws;
    unsigned short* q1 = us;
    unsigned short* k1 = us + 3670016;
    unsigned short* v1 = us + 7340032;
    unsigned short* q2 = us + 11010048;
    unsigned short* k2 = us + 14680064;
    unsigned short* v2 = us + 18350080;
    float* fb = (float*)d_ws + 11010048;
    unsigned short* ssb = (unsigned short*)fb;     // ssum bf16 [131072][56]
    unsigned short* aoutb = (unsigned short*)fb;   // aout bf16, overlays ssb
    unsigned short* c1o = (unsigned short*)(fb + 7340032);  // bf16 [16][16384][16]
    float* part = fb + 11534336;
    float* shif = fb + 11550720;
    float* P1T = fb + 11550752;
    float* P1M = fb + 11583520;
    float* P2R = fb + 11584032;
    float* P2M = fb + 12108320;
    unsigned short* WF = (unsigned short*)(fb + 12110368);
    unsigned short* WFo = WF + 11264;
    unsigned short* BF1 = WFo + 4096;   // 9216 u16 (hi 4608 | lo 4608)
    unsigned short* BF2 = BF1 + 9216;   // 4608 u16 (hi 2304 | lo 2304)
    float* P2T = (float*)(BF2 + 4608);  // [8][256][256] f32 (16B-aligned)
    float* outp = (float*)d_out;

    (void)hipFuncSetAttribute((const void*)k_qkv,
                              hipFuncAttributeMaxDynamicSharedMemorySize, 30720);
    (void)hipFuncSetAttribute((const void*)k_attn2,
                              hipFuncAttributeMaxDynamicSharedMemorySize, 66784);

    k_prep<<<87, 256, 0, stream>>>(Wq, Wkv, Wout, c1w, c2w, WF, WFo, BF1, BF2);
    k_qkv<<<2048, 256, 30720, stream>>>(x, WF, q1, k1, v1, q2, k2, v2, ssb);
    k_conv1<<<1024, 256, 0, stream>>>(ssb, BF1, c1b, c1o);
    k_conv2<<<1024, 256, 0, stream>>>(c1o, BF2, c2b, part);
    k_fc<<<1, 256, 0, stream>>>(part, f1w, f1b, f2w, f2b, shif);
    k_pos<<<2056, 256, 0, stream>>>(pos1, pos2, shif, P1T, P1M, P2R, P2M);
    k_posT<<<128, 256, 0, stream>>>(P2R, P2T);
    k_attn1<<<2048, 256, 0, stream>>>(q1, k1, v1, P1T, P1M, shif, aoutb);
    k_attn2<<<512, 512, 66784, stream>>>(q2, k2, v2, P2T, P2M, shif, aoutb);
    k_out<<<1024, 256, 0, stream>>>(aoutb, WFo, bout, outp);
}